// Round 12
// baseline (2714.905 us; speedup 1.0000x reference)
//
#include <hip/hip_runtime.h>
#include <hip/hip_bf16.h>
#include <math.h>

#define DEVFN static __device__ __forceinline__

DEVFN int clampi(int v, int lo, int hi){ return v < lo ? lo : (v > hi ? hi : v); }

// ---------------- small utility kernels ----------------

__global__ void k_zero(float* __restrict__ p, int n){
  int i = blockIdx.x*256 + threadIdx.x;
  if (i < n) p[i] = 0.f;
}

__global__ void k_filli(int* __restrict__ p, int n, int v){
  int i = blockIdx.x*256 + threadIdx.x;
  if (i < n) p[i] = v;
}

__global__ void k_fillf(float* __restrict__ p, int n, float v){
  int i = blockIdx.x*256 + threadIdx.x;
  if (i < n) p[i] = v;
}

__global__ void k_sqnorm(const float* __restrict__ x, float* __restrict__ sq, int n, int C){
  int i = blockIdx.x*256 + threadIdx.x;
  if (i >= n) return;
  const float* r = x + (size_t)i*C;
  float s = 0.f;
  for (int c = 0; c < C; ++c){ float v = r[c]; s += v*v; }
  sq[i] = s;
}

// ---------------- top-3 helpers ----------------

DEVFN void top3i(float d, int j, float& d0, float& d1, float& d2, int& i0, int& i1, int& i2){
  // strict '<': ascending-j processing keeps earliest j on ties (lax.top_k stable).
  if (d < d2){
    if (d < d1){
      d2 = d1; i2 = i1;
      if (d < d0){ d1 = d0; i1 = i0; d0 = d; i0 = j; }
      else       { d1 = d;  i1 = j; }
    } else { d2 = d; i2 = j; }
  }
}

DEVFN void top3t(float d, int j, float& d0, float& d1, float& d2, int& j0, int& j1, int& j2){
  // tie-aware (d equal -> smaller j wins) for merging pre-ranked candidate lists
  if (d < d2 || (d == d2 && j < j2)){
    if (d < d1 || (d == d1 && j < j1)){
      d2 = d1; j2 = j1;
      if (d < d0 || (d == d0 && j < j0)){ d1 = d0; j1 = j0; d0 = d; j0 = j; }
      else { d1 = d; j1 = j; }
    } else { d2 = d; j2 = j; }
  }
}

// ---------------- VALU knn v3: NO PRIVATE ARRAYS ----------------
// r9/r10/r11 evidence: private-array allocas in 256-thread kernels are demoted
// to scratch on this compiler regardless of idiom (VGPR=56, 71MB scratch
// traffic, 524us). v3 holds the thread's row in NAMED float4 SSA values
// (a0..a15) -- no alloca exists, so nothing can be demoted.

__global__ __launch_bounds__(256) void k_knn3_64(
    const float* __restrict__ x, const float* __restrict__ sq,
    int n_per, int nsplit, int csize,
    float* __restrict__ partd, int* __restrict__ parti)
{
  int s = blockIdx.x, tile = blockIdx.y, g = blockIdx.z;
  int tid = threadIdx.x;
  const float* xg = x  + (size_t)g*n_per*64;
  const float* sg = sq + (size_t)g*n_per;
  int ri = tile*256 + tid;
  const float* rp = xg + (size_t)ri*64;
  float4 a0 = *(const float4*)(rp+ 0), a1 = *(const float4*)(rp+ 4);
  float4 a2 = *(const float4*)(rp+ 8), a3 = *(const float4*)(rp+12);
  float4 a4 = *(const float4*)(rp+16), a5 = *(const float4*)(rp+20);
  float4 a6 = *(const float4*)(rp+24), a7 = *(const float4*)(rp+28);
  float4 a8 = *(const float4*)(rp+32), a9 = *(const float4*)(rp+36);
  float4 a10= *(const float4*)(rp+40), a11= *(const float4*)(rp+44);
  float4 a12= *(const float4*)(rp+48), a13= *(const float4*)(rp+52);
  float4 a14= *(const float4*)(rp+56), a15= *(const float4*)(rp+60);

  __shared__ float xs[128*64];
  __shared__ float ss[128];

  const float INF = __builtin_inff();
  float d0=INF,d1=INF,d2=INF; int j0=0,j1=0,j2=0;

  int jbase = s*csize;
  for (int t0 = jbase; t0 < jbase + csize; t0 += 128){
    __syncthreads();
    for (int idx = tid; idx < 128*64; idx += 256) xs[idx] = xg[(size_t)t0*64 + idx];
    if (tid < 128) ss[tid] = sg[t0 + tid];
    __syncthreads();
    for (int jj = 0; jj < 128; ++jj){
      const float* wr = xs + jj*64;
      float pa=0.f,pb=0.f,pc=0.f,pd=0.f;
#define KACC(A,OFF) { float4 w_ = *(const float4*)(wr+OFF); \
      pa += A.x*w_.x; pb += A.y*w_.y; pc += A.z*w_.z; pd += A.w*w_.w; }
      KACC(a0, 0) KACC(a1, 4) KACC(a2, 8) KACC(a3,12)
      KACC(a4,16) KACC(a5,20) KACC(a6,24) KACC(a7,28)
      KACC(a8,32) KACC(a9,36) KACC(a10,40) KACC(a11,44)
      KACC(a12,48) KACC(a13,52) KACC(a14,56) KACC(a15,60)
#undef KACC
      int j = t0 + jj;
      float v = fmaf(-2.f, (pa+pb)+(pc+pd), ss[jj]);   // rank value (q_i const/row)
      if (j != ri) top3i(v, j, d0,d1,d2, j0,j1,j2);
    }
  }
  size_t o = ((size_t)(g*n_per + ri)*nsplit + s)*3;
  partd[o+0]=d0; partd[o+1]=d1; partd[o+2]=d2;
  parti[o+0]=j0; parti[o+1]=j1; parti[o+2]=j2;
}

__global__ __launch_bounds__(256) void k_knn3_32(
    const float* __restrict__ x, const float* __restrict__ sq,
    int n_per, int nsplit, int csize,
    float* __restrict__ partd, int* __restrict__ parti)
{
  int s = blockIdx.x, tile = blockIdx.y, g = blockIdx.z;
  int tid = threadIdx.x;
  const float* xg = x  + (size_t)g*n_per*32;
  const float* sg = sq + (size_t)g*n_per;
  int ri0 = tile*512 + tid;
  int ri1 = ri0 + 256;
  const float* rp0 = xg + (size_t)ri0*32;
  const float* rp1 = xg + (size_t)ri1*32;
  float4 a0 = *(const float4*)(rp0+ 0), a1 = *(const float4*)(rp0+ 4);
  float4 a2 = *(const float4*)(rp0+ 8), a3 = *(const float4*)(rp0+12);
  float4 a4 = *(const float4*)(rp0+16), a5 = *(const float4*)(rp0+20);
  float4 a6 = *(const float4*)(rp0+24), a7 = *(const float4*)(rp0+28);
  float4 b0 = *(const float4*)(rp1+ 0), b1 = *(const float4*)(rp1+ 4);
  float4 b2 = *(const float4*)(rp1+ 8), b3 = *(const float4*)(rp1+12);
  float4 b4 = *(const float4*)(rp1+16), b5 = *(const float4*)(rp1+20);
  float4 b6 = *(const float4*)(rp1+24), b7 = *(const float4*)(rp1+28);

  __shared__ float xs[128*32];
  __shared__ float ss[128];

  const float INF = __builtin_inff();
  float d00=INF,d01=INF,d02=INF, d10=INF,d11=INF,d12=INF;
  int   n00=0,n01=0,n02=0, n10=0,n11=0,n12=0;

  int jbase = s*csize;
  for (int t0 = jbase; t0 < jbase + csize; t0 += 128){
    __syncthreads();
    for (int idx = tid; idx < 128*32; idx += 256) xs[idx] = xg[(size_t)t0*32 + idx];
    if (tid < 128) ss[tid] = sg[t0 + tid];
    __syncthreads();
    for (int jj = 0; jj < 128; ++jj){
      const float* wr = xs + jj*32;
      float pa0=0.f,pb0=0.f,pc0=0.f,pd0=0.f;
      float pa1=0.f,pb1=0.f,pc1=0.f,pd1=0.f;
#define KACC2(A,B,OFF) { float4 w_ = *(const float4*)(wr+OFF); \
      pa0 += A.x*w_.x; pb0 += A.y*w_.y; pc0 += A.z*w_.z; pd0 += A.w*w_.w; \
      pa1 += B.x*w_.x; pb1 += B.y*w_.y; pc1 += B.z*w_.z; pd1 += B.w*w_.w; }
      KACC2(a0,b0, 0) KACC2(a1,b1, 4) KACC2(a2,b2, 8) KACC2(a3,b3,12)
      KACC2(a4,b4,16) KACC2(a5,b5,20) KACC2(a6,b6,24) KACC2(a7,b7,28)
#undef KACC2
      int j = t0 + jj;
      float qs = ss[jj];
      float v0 = fmaf(-2.f, (pa0+pb0)+(pc0+pd0), qs);
      float v1 = fmaf(-2.f, (pa1+pb1)+(pc1+pd1), qs);
      if (j != ri0) top3i(v0, j, d00,d01,d02, n00,n01,n02);
      if (j != ri1) top3i(v1, j, d10,d11,d12, n10,n11,n12);
    }
  }
  {
    size_t o = ((size_t)(g*n_per + ri0)*nsplit + s)*3;
    partd[o+0]=d00; partd[o+1]=d01; partd[o+2]=d02;
    parti[o+0]=n00; parti[o+1]=n01; parti[o+2]=n02;
  }
  {
    size_t o = ((size_t)(g*n_per + ri1)*nsplit + s)*3;
    partd[o+0]=d10; partd[o+1]=d11; partd[o+2]=d12;
    parti[o+0]=n10; parti[o+1]=n11; parti[o+2]=n12;
  }
}

// ---------------- legacy VALU knn (800-node dyn knn only; 64-thr registerizes) ----------------

template<int C, int TJ>
__global__ __launch_bounds__(64) void k_knn(
    const float* __restrict__ x, const float* __restrict__ sq,
    int n_per, int bpg, int nsplit, int csize,
    float* __restrict__ partd, int* __restrict__ parti)
{
  int bid  = blockIdx.x;
  int s    = bid % nsplit;
  int b2i  = bid / nsplit;
  int g    = b2i / bpg;
  int tile = b2i % bpg;
  int tid  = threadIdx.x;
  int i0 = tile*128 + tid;
  int i1 = i0 + 64;
  const float* xg = x  + (size_t)g*n_per*C;
  const float* sg = sq + (size_t)g*n_per;
  bool a0 = i0 < n_per, a1 = i1 < n_per;
  float xi0[C], xi1[C];
  float q0 = 0.f, q1 = 0.f;
  if (a0){
    #pragma unroll
    for (int c = 0; c < C; ++c) xi0[c] = xg[(size_t)i0*C + c];
    q0 = sg[i0];
  } else {
    #pragma unroll
    for (int c = 0; c < C; ++c) xi0[c] = 0.f;
  }
  if (a1){
    #pragma unroll
    for (int c = 0; c < C; ++c) xi1[c] = xg[(size_t)i1*C + c];
    q1 = sg[i1];
  } else {
    #pragma unroll
    for (int c = 0; c < C; ++c) xi1[c] = 0.f;
  }
  __shared__ float xs[TJ*C];
  __shared__ float ss[TJ];
  float d00 = __builtin_inff(), d01 = __builtin_inff(), d02 = __builtin_inff();
  float d10 = __builtin_inff(), d11 = __builtin_inff(), d12 = __builtin_inff();
  int n00 = 0, n01 = 0, n02 = 0;
  int n10 = 0, n11 = 0, n12 = 0;

  int jbase = s*csize;
  int jend  = min(n_per, jbase + csize);
  for (int t0 = jbase; t0 < jend; t0 += TJ){
    int lim = min(TJ, jend - t0);
    __syncthreads();
    for (int idx = tid; idx < lim*C; idx += 64) xs[idx] = xg[(size_t)t0*C + idx];
    for (int idx = tid; idx < lim;   idx += 64) ss[idx] = sg[t0 + idx];
    __syncthreads();
    for (int jj = 0; jj < lim; ++jj){
      const float4* xr = (const float4*)(xs + jj*C);
      float p0a=0,p0b=0,p0c=0,p0d=0;
      float p1a=0,p1b=0,p1c=0,p1d=0;
      #pragma unroll
      for (int c4 = 0; c4 < C/4; ++c4){
        float4 w = xr[c4];
        p0a += xi0[4*c4+0]*w.x; p0b += xi0[4*c4+1]*w.y;
        p0c += xi0[4*c4+2]*w.z; p0d += xi0[4*c4+3]*w.w;
        p1a += xi1[4*c4+0]*w.x; p1b += xi1[4*c4+1]*w.y;
        p1c += xi1[4*c4+2]*w.z; p1d += xi1[4*c4+3]*w.w;
      }
      int j = t0 + jj;
      float dv0 = q0 + ss[jj] - 2.f*((p0a+p0b)+(p0c+p0d));
      float dv1 = q1 + ss[jj] - 2.f*((p1a+p1b)+(p1c+p1d));
      if (a0 && j != i0) top3i(dv0, j, d00,d01,d02, n00,n01,n02);
      if (a1 && j != i1) top3i(dv1, j, d10,d11,d12, n10,n11,n12);
    }
  }
  if (a0){
    size_t o = ((size_t)(g*n_per + i0)*nsplit + s)*3;
    partd[o+0]=d00; partd[o+1]=d01; partd[o+2]=d02;
    parti[o+0]=n00; parti[o+1]=n01; parti[o+2]=n02;
  }
  if (a1){
    size_t o = ((size_t)(g*n_per + i1)*nsplit + s)*3;
    partd[o+0]=d10; partd[o+1]=d11; partd[o+2]=d12;
    parti[o+0]=n10; parti[o+1]=n11; parti[o+2]=n12;
  }
}

__global__ void k_knnmerge(const float* __restrict__ partd, const int* __restrict__ parti,
                           int n_total, int n_per, int nsplit, int* __restrict__ nbr)
{
  int row = blockIdx.x*256 + threadIdx.x;
  if (row >= n_total) return;
  float d0 = __builtin_inff(), d1 = __builtin_inff(), d2 = __builtin_inff();
  int j0 = 0, j1 = 0, j2 = 0;
  for (int s = 0; s < nsplit; ++s){
    for (int q = 0; q < 3; ++q){
      size_t o = ((size_t)row*nsplit + s)*3 + q;
      float d = partd[o]; int j = parti[o];
      top3t(d, j, d0,d1,d2, j0,j1,j2);
    }
  }
  int g = row / n_per;
  nbr[row*3+0] = g*n_per + clampi(j0, 0, n_per-1);
  nbr[row*3+1] = g*n_per + clampi(j1, 0, n_per-1);
  nbr[row*3+2] = g*n_per + clampi(j2, 0, n_per-1);
}

// ---------------- Chebyshev conv pieces ----------------

__global__ void k_chebdn(const float* __restrict__ w, float* __restrict__ dn, int n){
  int i = blockIdx.x*256 + threadIdx.x;
  if (i >= n) return;
  float s = w[3*i] + w[3*i+1] + w[3*i+2];
  dn[i] = (s > 0.f) ? 1.f / sqrtf(fmaxf(s, 1e-12f)) : 0.f;
}

__global__ void k_chebwn(const float* __restrict__ w, const int* __restrict__ nbr,
                         const float* __restrict__ dn, float* __restrict__ wn, int ne, int n){
  int e = blockIdx.x*256 + threadIdx.x;
  if (e >= ne) return;
  int s = clampi(nbr[e], 0, n-1);
  wn[e] = w[e] * dn[e/3] * dn[s];
}

// out = aa * lap(v) + bb * zp ;  lap(v)[i] = -sum_k wn[3i+k] * v[src_k]
template<int C>
__global__ void k_lap(const float* __restrict__ v, const float* __restrict__ zp,
                      const float* __restrict__ wn, const int* __restrict__ nbr,
                      float* __restrict__ out, int total, float aa, float bb)
{
  int idx = blockIdx.x*256 + threadIdx.x;
  if (idx >= total) return;
  int i = idx / C;
  int c = idx - i*C;
  int e = i*3;
  int nmax = total / C;
  int s0 = clampi(nbr[e+0], 0, nmax-1);
  int s1 = clampi(nbr[e+1], 0, nmax-1);
  int s2 = clampi(nbr[e+2], 0, nmax-1);
  float s = wn[e+0]*v[(size_t)s0*C + c]
          + wn[e+1]*v[(size_t)s1*C + c]
          + wn[e+2]*v[(size_t)s2*C + c];
  float r = -aa*s;
  if (bb != 0.f) r += bb*zp[idx];
  out[idx] = r;
}

// ---------------- generic tiled matmul (acc in named float4s -- no alloca) ----------------

struct In4 { const float* p0; const float* p1; const float* p2; const float* p3; };

#define SELUF(v) (1.0507009873554805f * ((v) > 0.f ? (v) : 1.6732632423543772f * expm1f(v)))

template<int ACT, int NIN>
__global__ __launch_bounds__(256) void k_mm(
    In4 ins, const float* __restrict__ W,
    const float* __restrict__ bias, float* __restrict__ out,
    int nrows, int cin, int cout)
{
  __shared__ float inl[64][65];
  __shared__ float wl[64][64];
  int r0 = blockIdx.x * 64;
  int c0 = blockIdx.y * 64;
  int tid = threadIdx.x;
  int tr = tid & 15, tc = tid >> 4;
  float4 acc0 = {0,0,0,0}, acc1 = {0,0,0,0}, acc2 = {0,0,0,0}, acc3 = {0,0,0,0};
  const float* inp[4] = {ins.p0, ins.p1, ins.p2, ins.p3};
  for (int ni = 0; ni < NIN; ++ni){
    const float* A = inp[ni];
    const float* Wb = W + (size_t)ni*cin*cout;
    for (int k0 = 0; k0 < cin; k0 += 64){
      int klim = min(64, cin - k0);
      __syncthreads();
      for (int idx = tid; idx < 64*64; idx += 256){
        int rr = idx >> 6, kk = idx & 63;
        float v = 0.f;
        if (r0 + rr < nrows && kk < klim) v = A[(size_t)(r0+rr)*cin + k0 + kk];
        inl[rr][kk] = v;
      }
      for (int idx = tid; idx < 64*64; idx += 256){
        int kk = idx >> 6, jj = idx & 63;
        float v = 0.f;
        if (kk < klim && c0 + jj < cout) v = Wb[(size_t)(k0+kk)*cout + c0 + jj];
        wl[kk][jj] = v;
      }
      __syncthreads();
      for (int kk = 0; kk < 64; ++kk){
        float4 wv = *(const float4*)&wl[kk][tc*4];
        float a0v = inl[tr*4+0][kk];
        float a1v = inl[tr*4+1][kk];
        float a2v = inl[tr*4+2][kk];
        float a3v = inl[tr*4+3][kk];
        acc0.x += a0v*wv.x; acc0.y += a0v*wv.y; acc0.z += a0v*wv.z; acc0.w += a0v*wv.w;
        acc1.x += a1v*wv.x; acc1.y += a1v*wv.y; acc1.z += a1v*wv.z; acc1.w += a1v*wv.w;
        acc2.x += a2v*wv.x; acc2.y += a2v*wv.y; acc2.z += a2v*wv.z; acc2.w += a2v*wv.w;
        acc3.x += a3v*wv.x; acc3.y += a3v*wv.y; acc3.z += a3v*wv.z; acc3.w += a3v*wv.w;
      }
    }
  }
#define MM_EPI(AV, Q) { \
    int r = r0 + tr*4 + Q; \
    if (r < nrows){ \
      int jb = c0 + tc*4; float vv; \
      if (jb+0 < cout){ vv = AV.x + bias[jb+0]; if (ACT==1) vv=fmaxf(vv,0.f); if (ACT==2) vv=SELUF(vv); out[(size_t)r*cout + jb+0] = vv; } \
      if (jb+1 < cout){ vv = AV.y + bias[jb+1]; if (ACT==1) vv=fmaxf(vv,0.f); if (ACT==2) vv=SELUF(vv); out[(size_t)r*cout + jb+1] = vv; } \
      if (jb+2 < cout){ vv = AV.z + bias[jb+2]; if (ACT==1) vv=fmaxf(vv,0.f); if (ACT==2) vv=SELUF(vv); out[(size_t)r*cout + jb+2] = vv; } \
      if (jb+3 < cout){ vv = AV.w + bias[jb+3]; if (ACT==1) vv=fmaxf(vv,0.f); if (ACT==2) vv=SELUF(vv); out[(size_t)r*cout + jb+3] = vv; } \
    } }
  MM_EPI(acc0, 0)
  MM_EPI(acc1, 1)
  MM_EPI(acc2, 2)
  MM_EPI(acc3, 3)
#undef MM_EPI
}

// ---------------- GraphNorm ----------------

__global__ void k_gnstat(const float* __restrict__ x, float* __restrict__ msum,
                         float* __restrict__ m2sum)
{
  int g = blockIdx.x >> 4, chunk = blockIdx.x & 15;
  int c = threadIdx.x & 63, q = threadIdx.x >> 6;
  const float* xg = x + (size_t)g*4096*64;
  int nb = chunk*256;
  float s1 = 0.f, s2 = 0.f;
  for (int n = nb + q; n < nb + 256; n += 4){
    float v = xg[(size_t)n*64 + c];
    s1 += v; s2 += v*v;
  }
  __shared__ float r1[4][64], r2[4][64];
  r1[q][c] = s1; r2[q][c] = s2;
  __syncthreads();
  if (q == 0){
    atomicAdd(&msum[g*64 + c],  r1[0][c]+r1[1][c]+r1[2][c]+r1[3][c]);
    atomicAdd(&m2sum[g*64 + c], r2[0][c]+r2[1][c]+r2[2][c]+r2[3][c]);
  }
}

__global__ void k_gnapply(float* __restrict__ x, const float* __restrict__ msum,
                          const float* __restrict__ m2sum,
                          const float* __restrict__ alpha, const float* __restrict__ gamma,
                          const float* __restrict__ beta)
{
  int idx = blockIdx.x*256 + threadIdx.x;
  if (idx >= 32768*64) return;
  int c = idx & 63;
  int node = idx >> 6;
  int g = node >> 12;
  float m  = msum[g*64 + c]  * (1.f/4096.f);
  float e2 = m2sum[g*64 + c] * (1.f/4096.f);
  float al = alpha[c];
  float var = e2 - (2.f*al - al*al)*m*m;
  float sub = x[idx] - al*m;
  x[idx] = gamma[c] * sub * (1.f/sqrtf(fmaxf(var, 0.f) + 1e-5f)) + beta[c];
}

// ---------------- softmax (3-pass, no private array) + DiffPool ----------------

__global__ void k_softmax(const float* __restrict__ u, float* __restrict__ S, int n){
  int i = blockIdx.x*256 + threadIdx.x;
  if (i >= n) return;
  const float* r = u + (size_t)i*100;
  float* o = S + (size_t)i*100;
  float m = -__builtin_inff();
  for (int j = 0; j < 100; ++j) m = fmaxf(m, r[j]);
  float ssum = 0.f;
  for (int j = 0; j < 100; ++j) ssum += expf(r[j] - m);
  float inv = 1.f / ssum;
  for (int j = 0; j < 100; ++j) o[j] = expf(r[j] - m) * inv;
}

__global__ void k_pool(const float* __restrict__ S, const float* __restrict__ xf,
                       float* __restrict__ PT)
{
  int g = blockIdx.x >> 4, chunk = blockIdx.x & 15;
  int tid = threadIdx.x;
  __shared__ float Sl[64*100];
  __shared__ float Xl[64*32];
  float acc[13];
  int mq[13], cq[13];
  int base = tid*13;
  #pragma unroll
  for (int q = 0; q < 13; ++q){
    acc[q] = 0.f;
    int oi = base + q;
    mq[q] = (oi < 3300) ? oi/33 : 0;
    cq[q] = (oi < 3300) ? oi%33 : 0;
  }
  const float* Sg = S  + ((size_t)g*4096 + chunk*256)*100;
  const float* Xg = xf + ((size_t)g*4096 + chunk*256)*32;
  for (int n0 = 0; n0 < 256; n0 += 64){
    __syncthreads();
    for (int idx = tid; idx < 6400; idx += 256) Sl[idx] = Sg[(size_t)n0*100 + idx];
    for (int idx = tid; idx < 2048; idx += 256) Xl[idx] = Xg[(size_t)n0*32 + idx];
    __syncthreads();
    for (int nn = 0; nn < 64; ++nn){
      #pragma unroll
      for (int q = 0; q < 13; ++q){
        int ci = cq[q] & 31;
        float xv = Xl[nn*32 + ci];
        if (cq[q] == 32) xv = 1.f;
        acc[q] += Sl[nn*100 + mq[q]] * xv;
      }
    }
  }
  #pragma unroll
  for (int q = 0; q < 13; ++q){
    int oi = base + q;
    if (oi < 3300) atomicAdd(&PT[(size_t)g*3300 + oi], acc[q]);
  }
}

__global__ void k_xp(const float* __restrict__ PT, float* __restrict__ xp){
  int i = blockIdx.x*256 + threadIdx.x;
  if (i >= 800*32) return;
  int bm = i >> 5, c = i & 31;
  xp[i] = PT[(size_t)bm*33 + c] / PT[(size_t)bm*33 + 32];
}

// ---------------- PPI EdgeConv ----------------

__global__ void k_ppi(const float* __restrict__ xp, const int* __restrict__ connect,
                      const float* __restrict__ W2, const float* __restrict__ b2v,
                      int* __restrict__ hraw)
{
  int idx = blockIdx.x*256 + threadIdx.x;
  if (idx >= 8*600*64) return;
  int c  = idx & 63;
  int eg = idx >> 6;
  int b  = eg / 600, e = eg - b*600;
  int sI = b*100 + clampi(connect[e],       0, 99);
  int dI = b*100 + clampi(connect[600 + e], 0, 99);
  float acc = b2v[c];
  #pragma unroll
  for (int t = 0; t < 32; ++t) acc += xp[(size_t)dI*32 + t] * W2[t*64 + c];
  #pragma unroll
  for (int t = 0; t < 32; ++t) acc += (xp[(size_t)sI*32 + t] - xp[(size_t)dI*32 + t]) * W2[(32+t)*64 + c];
  float r = fmaxf(acc, 0.f);
  atomicMax(&hraw[(size_t)dI*64 + c], __float_as_int(r));
}

__global__ void k_hfin(const int* __restrict__ hraw, float* __restrict__ h, int n){
  int i = blockIdx.x*256 + threadIdx.x;
  if (i >= n) return;
  float v = __int_as_float(hraw[i]);
  h[i] = (v < -1e37f) ? 0.f : v;
}

// ---------------- Dynamic EdgeConv + residual ----------------

__global__ void k_dyn(const float* __restrict__ h, const int* __restrict__ nbr3,
                      const float* __restrict__ W3, const float* __restrict__ b3v,
                      float* __restrict__ z)
{
  int idx = blockIdx.x*256 + threadIdx.x;
  if (idx >= 800*64) return;
  int c = idx & 63, i = idx >> 6;
  float base = b3v[c];
  for (int t = 0; t < 64; ++t) base += h[(size_t)i*64 + t] * W3[t*64 + c];
  float mx = 0.f;
  for (int k = 0; k < 3; ++k){
    int sI = clampi(nbr3[i*3 + k], 0, 799);
    float acc = base;
    for (int t = 0; t < 64; ++t) acc += (h[(size_t)sI*64 + t] - h[(size_t)i*64 + t]) * W3[(64+t)*64 + c];
    mx = fmaxf(mx, fmaxf(acc, 0.f));
  }
  z[idx] = h[idx] + mx;
}

// ---------------- host launch ----------------

extern "C" void kernel_launch(void* const* d_in, const int* in_sizes, int n_in,
                              void* d_out, int out_size, void* d_ws, size_t ws_size,
                              hipStream_t stream)
{
  const size_t REQ = 11785728ull * 4ull;
  if (ws_size < REQ || n_in < 27){
    int nb = (out_size + 255)/256;
    k_fillf<<<nb, 256, 0, stream>>>((float*)d_out, out_size, (float)ws_size);
    return;
  }

  const float* x    = (const float*)d_in[0];
  const float* ew   = (const float*)d_in[1];
  const int*  connect = (const int*)d_in[3];
  const float* W0  = (const float*)d_in[4];
  const float* b0  = (const float*)d_in[5];
  const float* gal = (const float*)d_in[6];
  const float* gga = (const float*)d_in[7];
  const float* gbe = (const float*)d_in[8];
  const float* W1  = (const float*)d_in[9];
  const float* b1c = (const float*)d_in[10];
  const float* f1w1=(const float*)d_in[11]; const float* f1b1=(const float*)d_in[12];
  const float* f1w2=(const float*)d_in[13]; const float* f1b2=(const float*)d_in[14];
  const float* f1w3=(const float*)d_in[15]; const float* f1b3=(const float*)d_in[16];
  const float* W2  = (const float*)d_in[17]; const float* b2v=(const float*)d_in[18];
  const float* W3  = (const float*)d_in[19]; const float* b3v=(const float*)d_in[20];
  const float* f2w1=(const float*)d_in[21]; const float* f2b1=(const float*)d_in[22];
  const float* f2w2=(const float*)d_in[23]; const float* f2b2=(const float*)d_in[24];
  const float* f2w3=(const float*)d_in[25]; const float* f2b3=(const float*)d_in[26];

  float* ws   = (float*)d_ws;
  float* u0   = ws;                       // 2,097,152   (N x 64)
  float* Za   = ws +  2097152;            // 2,097,152
  float* Zb   = ws +  4194304;            // 2,097,152
  float* Zc   = ws +  6291456;            // 2,097,152
  float* arena= ws +  8388608;            // 2,883,584 (acc/h1/h2 only)
  float* acc  = arena;                    //   1,638,400 (4096 x 400)
  float* h1   = arena + 1638400;          //     819,200
  float* h2   = arena + 2457600;          //     409,600
  float* partd= Za;                       // knn partials in dead Za/Zb
  int*   parti= (int*)Zb;
  float* Sb   = Za;                       // 3,276,800 (aliases Za+Zb, post-conv)
  float* sm   = ws + 11272192;
  float* sqb  = sm;                       // 32,768
  float* dnb  = sm + 32768;               // 32,768
  float* wnb  = sm + 65536;               // 98,304
  int*   nbr  = (int*)(sm + 163840);      // 98,304
  int*   nbr3 = (int*)(sm + 262144);      // 2,400
  float* PT   = sm + 266240;              // 26,400
  float* xp   = sm + 294912;              // 25,600
  int*   hraw = (int*)(sm + 320512);      // 51,200
  float* hb   = sm + 371712;              // 51,200
  float* zb   = sm + 422912;              // 51,200
  float* g1   = sm + 474112;              // 25,600
  float* g2   = sm + 499712;              // 12,800
  float* gnb  = sm + 512512;              // 1,024

  float* ub   = (float*)d_out;            // u: 3,276,800 fp32
  float* vout = ub + 3276800;             // v: 12,800 fp32

  const int N = 32768;

  // 1) kNN #1 on x (C=32): named-float4 rows, nsplit=16, 2 rows/thread
  k_sqnorm<<<128, 256, 0, stream>>>(x, sqb, N, 32);
  k_knn3_32<<<dim3(16,8,8), 256, 0, stream>>>(x, sqb, 4096, 16, 256, partd, parti);
  k_knnmerge<<<128, 256, 0, stream>>>(partd, parti, N, 4096, 16, nbr);

  // 2) cheb normalization
  k_chebdn<<<128, 256, 0, stream>>>(ew, dnb, N);
  k_chebwn<<<384, 256, 0, stream>>>(ew, nbr, dnb, wnb, 3*N, N);

  // 3) conv0: Z recurrence (C=32), fused matmul 4x(32->64)
  k_lap<32><<<4096, 256, 0, stream>>>(x, x, wnb, nbr, Za, N*32, 1.f, 0.f);
  k_lap<32><<<4096, 256, 0, stream>>>(Za, x, wnb, nbr, Zb, N*32, 2.f, -1.f);
  k_lap<32><<<4096, 256, 0, stream>>>(Zb, Za, wnb, nbr, Zc, N*32, 2.f, -1.f);
  {
    In4 ins{x, Za, Zb, Zc};
    k_mm<0,4><<<dim3(512,1), 256, 0, stream>>>(ins, W0, b0, u0, N, 32, 64);
  }

  // 4) GraphNorm (in place on u0)
  k_zero<<<4, 256, 0, stream>>>(gnb, 1024);
  k_gnstat<<<128, 256, 0, stream>>>(u0, gnb, gnb + 512);
  k_gnapply<<<8192, 256, 0, stream>>>(u0, gnb, gnb + 512, gal, gga, gbe);

  // 5) kNN #2 on u0 (C=64): named-float4 rows, 1 row/thread
  k_sqnorm<<<128, 256, 0, stream>>>(u0, sqb, N, 64);
  k_knn3_64<<<dim3(16,16,8), 256, 0, stream>>>(u0, sqb, 4096, 16, 256, partd, parti);
  k_knnmerge<<<128, 256, 0, stream>>>(partd, parti, N, 4096, 16, nbr);
  k_chebwn<<<384, 256, 0, stream>>>(ew, nbr, dnb, wnb, 3*N, N);

  // 6) conv1 Z recurrence (C=64)
  k_lap<64><<<8192, 256, 0, stream>>>(u0, u0, wnb, nbr, Za, N*64, 1.f, 0.f);
  k_lap<64><<<8192, 256, 0, stream>>>(Za, u0, wnb, nbr, Zb, N*64, 2.f, -1.f);
  k_lap<64><<<8192, 256, 0, stream>>>(Zb, Za, wnb, nbr, Zc, N*64, 2.f, -1.f);

  // 7) chunked conv1-matmul + fc1 -> u in d_out
  for (int ch = 0; ch < 8; ++ch){
    size_t o64  = (size_t)ch*4096*64;
    size_t o100 = (size_t)ch*4096*100;
    In4 ic{u0 + o64, Za + o64, Zb + o64, Zc + o64};
    k_mm<0,4><<<dim3(64,7), 256, 0, stream>>>(ic, W1, b1c, acc, 4096, 64, 400);
    In4 i1{acc, nullptr, nullptr, nullptr};
    k_mm<2,1><<<dim3(64,4), 256, 0, stream>>>(i1, f1w1, f1b1, h1, 4096, 400, 200);
    In4 i2{h1, nullptr, nullptr, nullptr};
    k_mm<2,1><<<dim3(64,2), 256, 0, stream>>>(i2, f1w2, f1b2, h2, 4096, 200, 100);
    In4 i3{h2, nullptr, nullptr, nullptr};
    k_mm<0,1><<<dim3(64,2), 256, 0, stream>>>(i3, f1w3, f1b3, ub + o100, 4096, 100, 100);
  }

  // 8) DiffPool
  k_softmax<<<128, 256, 0, stream>>>(ub, Sb, N);
  k_zero<<<104, 256, 0, stream>>>(PT, 26400);
  k_pool<<<128, 256, 0, stream>>>(Sb, x, PT);
  k_xp<<<100, 256, 0, stream>>>(PT, xp);

  // 9) PPI EdgeConv
  k_filli<<<200, 256, 0, stream>>>(hraw, 51200, (int)0xFF800000);
  k_ppi<<<1200, 256, 0, stream>>>(xp, connect, W2, b2v, hraw);
  k_hfin<<<200, 256, 0, stream>>>(hraw, hb, 51200);

  // 10) Dynamic EdgeConv (small, legacy path)
  k_sqnorm<<<4, 256, 0, stream>>>(hb, sqb, 800, 64);
  k_knn<64,64><<<8, 64, 0, stream>>>(hb, sqb, 100, 1, 1, 100, partd, parti);
  k_knnmerge<<<4, 256, 0, stream>>>(partd, parti, 800, 100, 1, nbr3);
  k_dyn<<<200, 256, 0, stream>>>(hb, nbr3, W3, b3v, zb);

  // 11) fc2 -> v in d_out
  {
    In4 j1{zb, nullptr, nullptr, nullptr};
    k_mm<2,1><<<dim3(13,1), 256, 0, stream>>>(j1, f2w1, f2b1, g1, 800, 64, 32);
    In4 j2{g1, nullptr, nullptr, nullptr};
    k_mm<2,1><<<dim3(13,1), 256, 0, stream>>>(j2, f2w2, f2b2, g2, 800, 32, 16);
    In4 j3{g2, nullptr, nullptr, nullptr};
    k_mm<0,1><<<dim3(13,1), 256, 0, stream>>>(j3, f2w3, f2b3, vout, 800, 16, 16);
  }
}

// Round 13
// 1851.010 us; speedup vs baseline: 1.4667x; 1.4667x over previous
//
#include <hip/hip_runtime.h>
#include <hip/hip_bf16.h>
#include <math.h>

#define DEVFN static __device__ __forceinline__

DEVFN int clampi(int v, int lo, int hi){ return v < lo ? lo : (v > hi ? hi : v); }

// ---------------- small utility kernels ----------------

__global__ void k_zero(float* __restrict__ p, int n){
  int i = blockIdx.x*256 + threadIdx.x;
  if (i < n) p[i] = 0.f;
}

__global__ void k_filli(int* __restrict__ p, int n, int v){
  int i = blockIdx.x*256 + threadIdx.x;
  if (i < n) p[i] = v;
}

__global__ void k_fillf(float* __restrict__ p, int n, float v){
  int i = blockIdx.x*256 + threadIdx.x;
  if (i < n) p[i] = v;
}

__global__ void k_sqnorm(const float* __restrict__ x, float* __restrict__ sq, int n, int C){
  int i = blockIdx.x*256 + threadIdx.x;
  if (i >= n) return;
  const float* r = x + (size_t)i*C;
  float s = 0.f;
  for (int c = 0; c < C; ++c){ float v = r[c]; s += v*v; }
  sq[i] = s;
}

// ---------------- top-3 helpers ----------------

DEVFN void top3i(float d, int j, float& d0, float& d1, float& d2, int& i0, int& i1, int& i2){
  // strict '<': ascending-j processing keeps earliest j on ties (lax.top_k stable).
  if (d < d2){
    if (d < d1){
      d2 = d1; i2 = i1;
      if (d < d0){ d1 = d0; i1 = i0; d0 = d; i0 = j; }
      else       { d1 = d;  i1 = j; }
    } else { d2 = d; i2 = j; }
  }
}

DEVFN void top3t(float d, int j, float& d0, float& d1, float& d2, int& j0, int& j1, int& j2){
  // tie-aware (d equal -> smaller j wins) for merging pre-ranked candidate lists
  if (d < d2 || (d == d2 && j < j2)){
    if (d < d1 || (d == d1 && j < j1)){
      d2 = d1; j2 = j1;
      if (d < d0 || (d == d0 && j < j0)){ d1 = d0; j1 = j0; d0 = d; j0 = j; }
      else { d1 = d; j1 = j; }
    } else { d2 = d; j2 = j; }
  }
}

// ---------------- VALU knn v2 (r9 best-round version, frozen) ----------------

template<int C, int ROWS>
__global__ __launch_bounds__(256) void k_knn2(
    const float* __restrict__ x, const float* __restrict__ sq,
    int n_per, int nsplit, int csize,
    float* __restrict__ partd, int* __restrict__ parti)
{
  int s    = blockIdx.x;
  int tile = blockIdx.y;
  int g    = blockIdx.z;
  int tid  = threadIdx.x;
  int rpb  = 256*ROWS;
  const float* xg = x  + (size_t)g*n_per*C;
  const float* sg = sq + (size_t)g*n_per;

  int   ri[ROWS];
  float xi[ROWS][C];
  #pragma unroll
  for (int rr = 0; rr < ROWS; ++rr){
    ri[rr] = tile*rpb + rr*256 + tid;
    #pragma unroll
    for (int c4 = 0; c4 < C/4; ++c4)
      *(float4*)&xi[rr][c4*4] = *(const float4*)(xg + (size_t)ri[rr]*C + c4*4);
  }

  __shared__ float xs[128*C];
  __shared__ float ss[128];

  const float INF = __builtin_inff();
  float d0[ROWS], d1[ROWS], d2[ROWS];
  int   j0[ROWS], j1[ROWS], j2[ROWS];
  #pragma unroll
  for (int rr = 0; rr < ROWS; ++rr){ d0[rr]=INF; d1[rr]=INF; d2[rr]=INF; j0[rr]=0; j1[rr]=0; j2[rr]=0; }

  int jbase = s*csize;
  for (int t0 = jbase; t0 < jbase + csize; t0 += 128){
    __syncthreads();
    {
      const float4* src = (const float4*)(xg + (size_t)t0*C);
      float4* dst = (float4*)xs;
      for (int idx = tid; idx < 128*C/4; idx += 256) dst[idx] = src[idx];
      if (tid < 128) ss[tid] = sg[t0 + tid];
    }
    __syncthreads();
    #pragma unroll 2
    for (int jj = 0; jj < 128; ++jj){
      float qs = ss[jj];
      const float4* xr = (const float4*)(xs + jj*C);
      int j = t0 + jj;
      #pragma unroll
      for (int rr = 0; rr < ROWS; ++rr){
        float pa=0.f, pb=0.f, pc=0.f, pd=0.f;
        #pragma unroll
        for (int c4 = 0; c4 < C/4; ++c4){
          float4 w = xr[c4];
          pa += xi[rr][4*c4+0]*w.x; pb += xi[rr][4*c4+1]*w.y;
          pc += xi[rr][4*c4+2]*w.z; pd += xi[rr][4*c4+3]*w.w;
        }
        float v = fmaf(-2.f, (pa+pb)+(pc+pd), qs);
        if (j != ri[rr]) top3i(v, j, d0[rr],d1[rr],d2[rr], j0[rr],j1[rr],j2[rr]);
      }
    }
  }

  #pragma unroll
  for (int rr = 0; rr < ROWS; ++rr){
    size_t o = ((size_t)(g*n_per + ri[rr])*nsplit + s)*3;
    partd[o+0]=d0[rr]; partd[o+1]=d1[rr]; partd[o+2]=d2[rr];
    parti[o+0]=j0[rr]; parti[o+1]=j1[rr]; parti[o+2]=j2[rr];
  }
}

// ---------------- legacy VALU knn (800-node dyn knn only) ----------------

template<int C, int TJ>
__global__ __launch_bounds__(64) void k_knn(
    const float* __restrict__ x, const float* __restrict__ sq,
    int n_per, int bpg, int nsplit, int csize,
    float* __restrict__ partd, int* __restrict__ parti)
{
  int bid  = blockIdx.x;
  int s    = bid % nsplit;
  int b2i  = bid / nsplit;
  int g    = b2i / bpg;
  int tile = b2i % bpg;
  int tid  = threadIdx.x;
  int i0 = tile*128 + tid;
  int i1 = i0 + 64;
  const float* xg = x  + (size_t)g*n_per*C;
  const float* sg = sq + (size_t)g*n_per;
  bool a0 = i0 < n_per, a1 = i1 < n_per;
  float xi0[C], xi1[C];
  float q0 = 0.f, q1 = 0.f;
  if (a0){
    #pragma unroll
    for (int c = 0; c < C; ++c) xi0[c] = xg[(size_t)i0*C + c];
    q0 = sg[i0];
  } else {
    #pragma unroll
    for (int c = 0; c < C; ++c) xi0[c] = 0.f;
  }
  if (a1){
    #pragma unroll
    for (int c = 0; c < C; ++c) xi1[c] = xg[(size_t)i1*C + c];
    q1 = sg[i1];
  } else {
    #pragma unroll
    for (int c = 0; c < C; ++c) xi1[c] = 0.f;
  }
  __shared__ float xs[TJ*C];
  __shared__ float ss[TJ];
  float d00 = __builtin_inff(), d01 = __builtin_inff(), d02 = __builtin_inff();
  float d10 = __builtin_inff(), d11 = __builtin_inff(), d12 = __builtin_inff();
  int n00 = 0, n01 = 0, n02 = 0;
  int n10 = 0, n11 = 0, n12 = 0;

  int jbase = s*csize;
  int jend  = min(n_per, jbase + csize);
  for (int t0 = jbase; t0 < jend; t0 += TJ){
    int lim = min(TJ, jend - t0);
    __syncthreads();
    for (int idx = tid; idx < lim*C; idx += 64) xs[idx] = xg[(size_t)t0*C + idx];
    for (int idx = tid; idx < lim;   idx += 64) ss[idx] = sg[t0 + idx];
    __syncthreads();
    for (int jj = 0; jj < lim; ++jj){
      const float4* xr = (const float4*)(xs + jj*C);
      float p0a=0,p0b=0,p0c=0,p0d=0;
      float p1a=0,p1b=0,p1c=0,p1d=0;
      #pragma unroll
      for (int c4 = 0; c4 < C/4; ++c4){
        float4 w = xr[c4];
        p0a += xi0[4*c4+0]*w.x; p0b += xi0[4*c4+1]*w.y;
        p0c += xi0[4*c4+2]*w.z; p0d += xi0[4*c4+3]*w.w;
        p1a += xi1[4*c4+0]*w.x; p1b += xi1[4*c4+1]*w.y;
        p1c += xi1[4*c4+2]*w.z; p1d += xi1[4*c4+3]*w.w;
      }
      int j = t0 + jj;
      float dv0 = q0 + ss[jj] - 2.f*((p0a+p0b)+(p0c+p0d));
      float dv1 = q1 + ss[jj] - 2.f*((p1a+p1b)+(p1c+p1d));
      if (a0 && j != i0) top3i(dv0, j, d00,d01,d02, n00,n01,n02);
      if (a1 && j != i1) top3i(dv1, j, d10,d11,d12, n10,n11,n12);
    }
  }
  if (a0){
    size_t o = ((size_t)(g*n_per + i0)*nsplit + s)*3;
    partd[o+0]=d00; partd[o+1]=d01; partd[o+2]=d02;
    parti[o+0]=n00; parti[o+1]=n01; parti[o+2]=n02;
  }
  if (a1){
    size_t o = ((size_t)(g*n_per + i1)*nsplit + s)*3;
    partd[o+0]=d10; partd[o+1]=d11; partd[o+2]=d12;
    parti[o+0]=n10; parti[o+1]=n11; parti[o+2]=n12;
  }
}

__global__ void k_knnmerge(const float* __restrict__ partd, const int* __restrict__ parti,
                           int n_total, int n_per, int nsplit, int* __restrict__ nbr)
{
  int row = blockIdx.x*256 + threadIdx.x;
  if (row >= n_total) return;
  float d0 = __builtin_inff(), d1 = __builtin_inff(), d2 = __builtin_inff();
  int j0 = 0, j1 = 0, j2 = 0;
  for (int s = 0; s < nsplit; ++s){
    for (int q = 0; q < 3; ++q){
      size_t o = ((size_t)row*nsplit + s)*3 + q;
      float d = partd[o]; int j = parti[o];
      top3t(d, j, d0,d1,d2, j0,j1,j2);
    }
  }
  int g = row / n_per;
  nbr[row*3+0] = g*n_per + clampi(j0, 0, n_per-1);
  nbr[row*3+1] = g*n_per + clampi(j1, 0, n_per-1);
  nbr[row*3+2] = g*n_per + clampi(j2, 0, n_per-1);
}

// ---------------- Chebyshev conv pieces ----------------
// chebwn v2: dn recomputed per-edge from w (deg of node i = w[3i]+w[3i+1]+w[3i+2])
// -> chebdn kernel and dn buffer eliminated.

__global__ void k_chebwn(const float* __restrict__ w, const int* __restrict__ nbr,
                         float* __restrict__ wn, int ne, int n){
  int e = blockIdx.x*256 + threadIdx.x;
  if (e >= ne) return;
  int i = e/3;
  int s = clampi(nbr[e], 0, n-1);
  float sd = w[3*i] + w[3*i+1] + w[3*i+2];
  float sv = w[3*s] + w[3*s+1] + w[3*s+2];
  float dnd = (sd > 0.f) ? 1.f / sqrtf(fmaxf(sd, 1e-12f)) : 0.f;
  float dns = (sv > 0.f) ? 1.f / sqrtf(fmaxf(sv, 1e-12f)) : 0.f;
  wn[e] = w[e] * dnd * dns;
}

// out = aa * lap(v) + bb * zp ;  lap(v)[i] = -sum_k wn[3i+k] * v[src_k]
template<int C>
__global__ void k_lap(const float* __restrict__ v, const float* __restrict__ zp,
                      const float* __restrict__ wn, const int* __restrict__ nbr,
                      float* __restrict__ out, int total, float aa, float bb)
{
  int idx = blockIdx.x*256 + threadIdx.x;
  if (idx >= total) return;
  int i = idx / C;
  int c = idx - i*C;
  int e = i*3;
  int nmax = total / C;
  int s0 = clampi(nbr[e+0], 0, nmax-1);
  int s1 = clampi(nbr[e+1], 0, nmax-1);
  int s2 = clampi(nbr[e+2], 0, nmax-1);
  float s = wn[e+0]*v[(size_t)s0*C + c]
          + wn[e+1]*v[(size_t)s1*C + c]
          + wn[e+2]*v[(size_t)s2*C + c];
  float r = -aa*s;
  if (bb != 0.f) r += bb*zp[idx];
  out[idx] = r;
}

// ---------------- generic tiled matmul (r9 best-round version, frozen) ----------------

struct In4 { const float* p0; const float* p1; const float* p2; const float* p3; };

template<int ACT, int NIN>
__global__ __launch_bounds__(256) void k_mm(
    In4 ins, const float* __restrict__ W,
    const float* __restrict__ bias, float* __restrict__ out,
    int nrows, int cin, int cout)
{
  __shared__ float inl[64][65];
  __shared__ float wl[64][64];
  int r0 = blockIdx.x * 64;
  int c0 = blockIdx.y * 64;
  int tid = threadIdx.x;
  int tr = tid & 15, tc = tid >> 4;
  float acc[4][4] = {{0,0,0,0},{0,0,0,0},{0,0,0,0},{0,0,0,0}};
  const float* inp[4] = {ins.p0, ins.p1, ins.p2, ins.p3};
  for (int ni = 0; ni < NIN; ++ni){
    const float* A = inp[ni];
    const float* Wb = W + (size_t)ni*cin*cout;
    for (int k0 = 0; k0 < cin; k0 += 64){
      int klim = min(64, cin - k0);
      __syncthreads();
      for (int idx = tid; idx < 64*64; idx += 256){
        int rr = idx >> 6, kk = idx & 63;
        float v = 0.f;
        if (r0 + rr < nrows && kk < klim) v = A[(size_t)(r0+rr)*cin + k0 + kk];
        inl[rr][kk] = v;
      }
      for (int idx = tid; idx < 64*64; idx += 256){
        int kk = idx >> 6, jj = idx & 63;
        float v = 0.f;
        if (kk < klim && c0 + jj < cout) v = Wb[(size_t)(k0+kk)*cout + c0 + jj];
        wl[kk][jj] = v;
      }
      __syncthreads();
      for (int kk = 0; kk < 64; ++kk){
        float4 wv = *(const float4*)&wl[kk][tc*4];
        float a0v = inl[tr*4+0][kk];
        float a1v = inl[tr*4+1][kk];
        float a2v = inl[tr*4+2][kk];
        float a3v = inl[tr*4+3][kk];
        acc[0][0] += a0v*wv.x; acc[0][1] += a0v*wv.y; acc[0][2] += a0v*wv.z; acc[0][3] += a0v*wv.w;
        acc[1][0] += a1v*wv.x; acc[1][1] += a1v*wv.y; acc[1][2] += a1v*wv.z; acc[1][3] += a1v*wv.w;
        acc[2][0] += a2v*wv.x; acc[2][1] += a2v*wv.y; acc[2][2] += a2v*wv.z; acc[2][3] += a2v*wv.w;
        acc[3][0] += a3v*wv.x; acc[3][1] += a3v*wv.y; acc[3][2] += a3v*wv.z; acc[3][3] += a3v*wv.w;
      }
    }
  }
  #pragma unroll
  for (int q = 0; q < 4; ++q){
    int r = r0 + tr*4 + q;
    if (r >= nrows) continue;
    #pragma unroll
    for (int p = 0; p < 4; ++p){
      int j = c0 + tc*4 + p;
      if (j >= cout) continue;
      float v = acc[q][p] + bias[j];
      if (ACT == 1) v = fmaxf(v, 0.f);
      if (ACT == 2) v = 1.0507009873554805f * (v > 0.f ? v : 1.6732632423543772f * expm1f(v));
      out[(size_t)r*cout + j] = v;
    }
  }
}

// ---------------- GraphNorm (non-atomic: per-chunk partials in scratch) ----------------

__global__ void k_gnstat(const float* __restrict__ x, float* __restrict__ msum_p,
                         float* __restrict__ m2sum_p)
{
  int g = blockIdx.x >> 4, chunk = blockIdx.x & 15;
  int c = threadIdx.x & 63, q = threadIdx.x >> 6;
  const float* xg = x + (size_t)g*4096*64;
  int nb = chunk*256;
  float s1 = 0.f, s2 = 0.f;
  for (int n = nb + q; n < nb + 256; n += 4){
    float v = xg[(size_t)n*64 + c];
    s1 += v; s2 += v*v;
  }
  __shared__ float r1[4][64], r2[4][64];
  r1[q][c] = s1; r2[q][c] = s2;
  __syncthreads();
  if (q == 0){
    msum_p [(g*16 + chunk)*64 + c] = r1[0][c]+r1[1][c]+r1[2][c]+r1[3][c];
    m2sum_p[(g*16 + chunk)*64 + c] = r2[0][c]+r2[1][c]+r2[2][c]+r2[3][c];
  }
}

__global__ void k_gnapply(float* __restrict__ x, const float* __restrict__ msum_p,
                          const float* __restrict__ m2sum_p,
                          const float* __restrict__ alpha, const float* __restrict__ gamma,
                          const float* __restrict__ beta)
{
  int idx = blockIdx.x*256 + threadIdx.x;
  if (idx >= 32768*64) return;
  int c = idx & 63;
  int node = idx >> 6;
  int g = node >> 12;
  float ms = 0.f, m2 = 0.f;
  for (int ch = 0; ch < 16; ++ch){
    ms += msum_p [(g*16 + ch)*64 + c];
    m2 += m2sum_p[(g*16 + ch)*64 + c];
  }
  float m  = ms * (1.f/4096.f);
  float e2 = m2 * (1.f/4096.f);
  float al = alpha[c];
  float var = e2 - (2.f*al - al*al)*m*m;
  float sub = x[idx] - al*m;
  x[idx] = gamma[c] * sub * (1.f/sqrtf(fmaxf(var, 0.f) + 1e-5f)) + beta[c];
}

// ---------------- softmax + DiffPool (r9 versions, frozen) ----------------

__global__ void k_softmax(const float* __restrict__ u, float* __restrict__ S, int n){
  int i = blockIdx.x*256 + threadIdx.x;
  if (i >= n) return;
  const float* r = u + (size_t)i*100;
  float* o = S + (size_t)i*100;
  float lr[100];
  float m = -__builtin_inff();
  for (int j = 0; j < 100; ++j){ lr[j] = r[j]; m = fmaxf(m, lr[j]); }
  float ssum = 0.f;
  for (int j = 0; j < 100; ++j){ lr[j] = expf(lr[j] - m); ssum += lr[j]; }
  float inv = 1.f / ssum;
  for (int j = 0; j < 100; ++j) o[j] = lr[j] * inv;
}

__global__ void k_pool(const float* __restrict__ S, const float* __restrict__ xf,
                       float* __restrict__ PT)
{
  int g = blockIdx.x >> 4, chunk = blockIdx.x & 15;
  int tid = threadIdx.x;
  __shared__ float Sl[64*100];
  __shared__ float Xl[64*32];
  float acc[13];
  int mq[13], cq[13];
  int base = tid*13;
  #pragma unroll
  for (int q = 0; q < 13; ++q){
    acc[q] = 0.f;
    int oi = base + q;
    mq[q] = (oi < 3300) ? oi/33 : 0;
    cq[q] = (oi < 3300) ? oi%33 : 0;
  }
  const float* Sg = S  + ((size_t)g*4096 + chunk*256)*100;
  const float* Xg = xf + ((size_t)g*4096 + chunk*256)*32;
  for (int n0 = 0; n0 < 256; n0 += 64){
    __syncthreads();
    for (int idx = tid; idx < 6400; idx += 256) Sl[idx] = Sg[(size_t)n0*100 + idx];
    for (int idx = tid; idx < 2048; idx += 256) Xl[idx] = Xg[(size_t)n0*32 + idx];
    __syncthreads();
    for (int nn = 0; nn < 64; ++nn){
      #pragma unroll
      for (int q = 0; q < 13; ++q){
        int ci = cq[q] & 31;
        float xv = Xl[nn*32 + ci];
        if (cq[q] == 32) xv = 1.f;
        acc[q] += Sl[nn*100 + mq[q]] * xv;
      }
    }
  }
  #pragma unroll
  for (int q = 0; q < 13; ++q){
    int oi = base + q;
    if (oi < 3300) atomicAdd(&PT[(size_t)g*3300 + oi], acc[q]);
  }
}

__global__ void k_xp(const float* __restrict__ PT, float* __restrict__ xp){
  int i = blockIdx.x*256 + threadIdx.x;
  if (i >= 800*32) return;
  int bm = i >> 5, c = i & 31;
  xp[i] = PT[(size_t)bm*33 + c] / PT[(size_t)bm*33 + 32];
}

// ---------------- PPI EdgeConv ----------------

__global__ void k_ppi(const float* __restrict__ xp, const int* __restrict__ connect,
                      const float* __restrict__ W2, const float* __restrict__ b2v,
                      int* __restrict__ hraw)
{
  int idx = blockIdx.x*256 + threadIdx.x;
  if (idx >= 8*600*64) return;
  int c  = idx & 63;
  int eg = idx >> 6;
  int b  = eg / 600, e = eg - b*600;
  int sI = b*100 + clampi(connect[e],       0, 99);
  int dI = b*100 + clampi(connect[600 + e], 0, 99);
  float acc = b2v[c];
  #pragma unroll
  for (int t = 0; t < 32; ++t) acc += xp[(size_t)dI*32 + t] * W2[t*64 + c];
  #pragma unroll
  for (int t = 0; t < 32; ++t) acc += (xp[(size_t)sI*32 + t] - xp[(size_t)dI*32 + t]) * W2[(32+t)*64 + c];
  float r = fmaxf(acc, 0.f);
  atomicMax(&hraw[(size_t)dI*64 + c], __float_as_int(r));
}

__global__ void k_hfin(const int* __restrict__ hraw, float* __restrict__ h, int n){
  int i = blockIdx.x*256 + threadIdx.x;
  if (i >= n) return;
  float v = __int_as_float(hraw[i]);
  h[i] = (v < -1e37f) ? 0.f : v;
}

// ---------------- Dynamic EdgeConv + residual ----------------

__global__ void k_dyn(const float* __restrict__ h, const int* __restrict__ nbr3,
                      const float* __restrict__ W3, const float* __restrict__ b3v,
                      float* __restrict__ z)
{
  int idx = blockIdx.x*256 + threadIdx.x;
  if (idx >= 800*64) return;
  int c = idx & 63, i = idx >> 6;
  float base = b3v[c];
  for (int t = 0; t < 64; ++t) base += h[(size_t)i*64 + t] * W3[t*64 + c];
  float mx = 0.f;
  for (int k = 0; k < 3; ++k){
    int sI = clampi(nbr3[i*3 + k], 0, 799);
    float acc = base;
    for (int t = 0; t < 64; ++t) acc += (h[(size_t)sI*64 + t] - h[(size_t)i*64 + t]) * W3[(64+t)*64 + c];
    mx = fmaxf(mx, fmaxf(acc, 0.f));
  }
  z[idx] = h[idx] + mx;
}

// ---------------- host launch ----------------

extern "C" void kernel_launch(void* const* d_in, const int* in_sizes, int n_in,
                              void* d_out, int out_size, void* d_ws, size_t ws_size,
                              hipStream_t stream)
{
  const size_t REQ_SMALL = 11785728ull * 4ull;     // 45.0 MiB (chunked path)
  const size_t REQ_BIG   = 31854592ull * 4ull;     // 121.5 MiB (dechunked path)
  if (ws_size < REQ_SMALL || n_in < 27){
    int nb = (out_size + 255)/256;
    k_fillf<<<nb, 256, 0, stream>>>((float*)d_out, out_size, (float)ws_size);
    return;
  }
  const bool big = (ws_size >= REQ_BIG);           // constant per deployment -> capture-safe

  const float* x    = (const float*)d_in[0];
  const float* ew   = (const float*)d_in[1];
  const int*  connect = (const int*)d_in[3];
  const float* W0  = (const float*)d_in[4];
  const float* b0  = (const float*)d_in[5];
  const float* gal = (const float*)d_in[6];
  const float* gga = (const float*)d_in[7];
  const float* gbe = (const float*)d_in[8];
  const float* W1  = (const float*)d_in[9];
  const float* b1c = (const float*)d_in[10];
  const float* f1w1=(const float*)d_in[11]; const float* f1b1=(const float*)d_in[12];
  const float* f1w2=(const float*)d_in[13]; const float* f1b2=(const float*)d_in[14];
  const float* f1w3=(const float*)d_in[15]; const float* f1b3=(const float*)d_in[16];
  const float* W2  = (const float*)d_in[17]; const float* b2v=(const float*)d_in[18];
  const float* W3  = (const float*)d_in[19]; const float* b3v=(const float*)d_in[20];
  const float* f2w1=(const float*)d_in[21]; const float* f2b1=(const float*)d_in[22];
  const float* f2w2=(const float*)d_in[23]; const float* f2b2=(const float*)d_in[24];
  const float* f2w3=(const float*)d_in[25]; const float* f2b3=(const float*)d_in[26];

  float* ws   = (float*)d_ws;
  float* u0   = ws;                       // 2,097,152   (N x 64)
  float* Za   = ws +  2097152;            // 2,097,152
  float* Zb   = ws +  4194304;            // 2,097,152
  float* Zc   = ws +  6291456;            // 2,097,152 (ends 8,388,608)
  // stage-7 arena: chunked (8,388,608..11,272,192) or full-size (8,388,608..31,326,208)
  float* acc  = ws +  8388608;            // chunked: 4096x400 | big: 32768x400
  float* h1   = big ? (ws + 21495808) : (acc + 1638400);
  float* h2   = big ? (ws + 28049408) : (acc + 2457600);
  float* partd= Za;                       // knn partials in dead Za/Zb
  int*   parti= (int*)Zb;
  float* Sb   = Za;                       // 3,276,800 (aliases Za+Zb, post-conv)
  float* sm   = big ? (ws + 31326208) : (ws + 11272192);  // smalls (528,384)
  float* sqb  = sm;                       // 32,768 (also GN partials: 16,384 used)
  int*   nbr  = (int*)(sm + 163840);      // 98,304
  int*   nbr3 = (int*)(sm + 262144);      // 2,400
  float* PT   = sm + 266240;              // 26,400
  float* xp   = sm + 294912;              // 25,600
  int*   hraw = (int*)(sm + 320512);      // 51,200
  float* hb   = sm + 371712;              // 51,200
  float* zb   = sm + 422912;              // 51,200
  float* g1   = sm + 474112;              // 25,600
  float* g2   = sm + 499712;              // 12,800
  float* wnb  = sm + 65536;               // 98,304

  float* ub   = (float*)d_out;            // u: 3,276,800 fp32
  float* vout = ub + 3276800;             // v: 12,800 fp32

  const int N = 32768;

  // 1) kNN #1 on x (C=32)
  k_sqnorm<<<128, 256, 0, stream>>>(x, sqb, N, 32);
  k_knn2<32,2><<<dim3(16,8,8), 256, 0, stream>>>(x, sqb, 4096, 16, 256, partd, parti);
  k_knnmerge<<<128, 256, 0, stream>>>(partd, parti, N, 4096, 16, nbr);

  // 2) cheb normalization (dn fused into chebwn)
  k_chebwn<<<384, 256, 0, stream>>>(ew, nbr, wnb, 3*N, N);

  // 3) conv0: Z recurrence (C=32), fused matmul 4x(32->64)
  k_lap<32><<<4096, 256, 0, stream>>>(x, x, wnb, nbr, Za, N*32, 1.f, 0.f);
  k_lap<32><<<4096, 256, 0, stream>>>(Za, x, wnb, nbr, Zb, N*32, 2.f, -1.f);
  k_lap<32><<<4096, 256, 0, stream>>>(Zb, Za, wnb, nbr, Zc, N*32, 2.f, -1.f);
  {
    In4 ins{x, Za, Zb, Zc};
    k_mm<0,4><<<dim3(512,1), 256, 0, stream>>>(ins, W0, b0, u0, N, 32, 64);
  }

  // 4) GraphNorm (non-atomic partials in sqb; sqb dead until step 5)
  k_gnstat<<<128, 256, 0, stream>>>(u0, sqb, sqb + 8192);
  k_gnapply<<<8192, 256, 0, stream>>>(u0, sqb, sqb + 8192, gal, gga, gbe);

  // 5) kNN #2 on u0 (C=64)
  k_sqnorm<<<128, 256, 0, stream>>>(u0, sqb, N, 64);
  k_knn2<64,1><<<dim3(16,16,8), 256, 0, stream>>>(u0, sqb, 4096, 16, 256, partd, parti);
  k_knnmerge<<<128, 256, 0, stream>>>(partd, parti, N, 4096, 16, nbr);
  k_chebwn<<<384, 256, 0, stream>>>(ew, nbr, wnb, 3*N, N);

  // 6) conv1 Z recurrence (C=64)
  k_lap<64><<<8192, 256, 0, stream>>>(u0, u0, wnb, nbr, Za, N*64, 1.f, 0.f);
  k_lap<64><<<8192, 256, 0, stream>>>(Za, u0, wnb, nbr, Zb, N*64, 2.f, -1.f);
  k_lap<64><<<8192, 256, 0, stream>>>(Zb, Za, wnb, nbr, Zc, N*64, 2.f, -1.f);

  // 7) conv1-matmul + fc1 -> u in d_out. Dechunked (full grids) when ws allows.
  {
    int nch  = big ? 1 : 8;
    int rows = big ? N : 4096;
    int gx   = big ? 512 : 64;
    for (int ch = 0; ch < nch; ++ch){
      size_t o64  = (size_t)ch*4096*64;
      size_t o100 = (size_t)ch*4096*100;
      In4 ic{u0 + o64, Za + o64, Zb + o64, Zc + o64};
      k_mm<0,4><<<dim3(gx,7), 256, 0, stream>>>(ic, W1, b1c, acc, rows, 64, 400);
      In4 i1{acc, nullptr, nullptr, nullptr};
      k_mm<2,1><<<dim3(gx,4), 256, 0, stream>>>(i1, f1w1, f1b1, h1, rows, 400, 200);
      In4 i2{h1, nullptr, nullptr, nullptr};
      k_mm<2,1><<<dim3(gx,2), 256, 0, stream>>>(i2, f1w2, f1b2, h2, rows, 200, 100);
      In4 i3{h2, nullptr, nullptr, nullptr};
      k_mm<0,1><<<dim3(gx,2), 256, 0, stream>>>(i3, f1w3, f1b3, ub + o100, rows, 100, 100);
    }
  }

  // 8) DiffPool
  k_softmax<<<128, 256, 0, stream>>>(ub, Sb, N);
  k_zero<<<104, 256, 0, stream>>>(PT, 26400);
  k_pool<<<128, 256, 0, stream>>>(Sb, x, PT);
  k_xp<<<100, 256, 0, stream>>>(PT, xp);

  // 9) PPI EdgeConv
  k_filli<<<200, 256, 0, stream>>>(hraw, 51200, (int)0xFF800000);
  k_ppi<<<1200, 256, 0, stream>>>(xp, connect, W2, b2v, hraw);
  k_hfin<<<200, 256, 0, stream>>>(hraw, hb, 51200);

  // 10) Dynamic EdgeConv (small, legacy path)
  k_sqnorm<<<4, 256, 0, stream>>>(hb, sqb, 800, 64);
  k_knn<64,64><<<8, 64, 0, stream>>>(hb, sqb, 100, 1, 1, 100, partd, parti);
  k_knnmerge<<<4, 256, 0, stream>>>(partd, parti, 800, 100, 1, nbr3);
  k_dyn<<<200, 256, 0, stream>>>(hb, nbr3, W3, b3v, zb);

  // 11) fc2 -> v in d_out
  {
    In4 j1{zb, nullptr, nullptr, nullptr};
    k_mm<2,1><<<dim3(13,1), 256, 0, stream>>>(j1, f2w1, f2b1, g1, 800, 64, 32);
    In4 j2{g1, nullptr, nullptr, nullptr};
    k_mm<2,1><<<dim3(13,1), 256, 0, stream>>>(j2, f2w2, f2b2, g2, 800, 32, 16);
    In4 j3{g2, nullptr, nullptr, nullptr};
    k_mm<0,1><<<dim3(13,1), 256, 0, stream>>>(j3, f2w3, f2b3, vout, 800, 16, 16);
  }
}

// Round 14
// 1764.324 us; speedup vs baseline: 1.5388x; 1.0491x over previous
//
#include <hip/hip_runtime.h>
#include <hip/hip_bf16.h>
#include <math.h>

#define DEVFN static __device__ __forceinline__

DEVFN int clampi(int v, int lo, int hi){ return v < lo ? lo : (v > hi ? hi : v); }

// ---------------- small utility kernels ----------------

__global__ void k_zero(float* __restrict__ p, int n){
  int i = blockIdx.x*256 + threadIdx.x;
  if (i < n) p[i] = 0.f;
}

__global__ void k_filli(int* __restrict__ p, int n, int v){
  int i = blockIdx.x*256 + threadIdx.x;
  if (i < n) p[i] = v;
}

__global__ void k_fillf(float* __restrict__ p, int n, float v){
  int i = blockIdx.x*256 + threadIdx.x;
  if (i < n) p[i] = v;
}

__global__ void k_sqnorm(const float* __restrict__ x, float* __restrict__ sq, int n, int C){
  int i = blockIdx.x*256 + threadIdx.x;
  if (i >= n) return;
  const float* r = x + (size_t)i*C;
  float s = 0.f;
  for (int c = 0; c < C; ++c){ float v = r[c]; s += v*v; }
  sq[i] = s;
}

// ---------------- top-3 helpers ----------------

DEVFN void top3i(float d, int j, float& d0, float& d1, float& d2, int& i0, int& i1, int& i2){
  // strict '<': ascending-j processing keeps earliest j on ties (lax.top_k stable).
  if (d < d2){
    if (d < d1){
      d2 = d1; i2 = i1;
      if (d < d0){ d1 = d0; i1 = i0; d0 = d; i0 = j; }
      else       { d1 = d;  i1 = j; }
    } else { d2 = d; i2 = j; }
  }
}

DEVFN void top3t(float d, int j, float& d0, float& d1, float& d2, int& j0, int& j1, int& j2){
  // tie-aware (d equal -> smaller j wins) for merging pre-ranked candidate lists
  if (d < d2 || (d == d2 && j < j2)){
    if (d < d1 || (d == d1 && j < j1)){
      d2 = d1; j2 = j1;
      if (d < d0 || (d == d0 && j < j0)){ d1 = d0; j1 = j0; d0 = d; j0 = j; }
      else { d1 = d; j1 = j; }
    } else { d2 = d; j2 = j; }
  }
}

// ---------------- VALU knn, 64-thread registerized (r4 idiom) ----------------
// r4 is the ONLY variant the allocator registerized (VGPR=108). Its limiter was
// occupancy (16.9KB LDS -> ~7 waves/CU). This round: same template, smaller
// j-tile TJ -> 8.4KB LDS -> ~16-19 blocks/CU. 2 rows/thread (C=32).

template<int C, int TJ>
__global__ __launch_bounds__(64) void k_knn(
    const float* __restrict__ x, const float* __restrict__ sq,
    int n_per, int bpg, int nsplit, int csize,
    float* __restrict__ partd, int* __restrict__ parti)
{
  int bid  = blockIdx.x;
  int s    = bid % nsplit;
  int b2i  = bid / nsplit;
  int g    = b2i / bpg;
  int tile = b2i % bpg;
  int tid  = threadIdx.x;
  int i0 = tile*128 + tid;
  int i1 = i0 + 64;
  const float* xg = x  + (size_t)g*n_per*C;
  const float* sg = sq + (size_t)g*n_per;
  bool a0 = i0 < n_per, a1 = i1 < n_per;
  float xi0[C], xi1[C];
  float q0 = 0.f, q1 = 0.f;
  if (a0){
    #pragma unroll
    for (int c = 0; c < C; ++c) xi0[c] = xg[(size_t)i0*C + c];
    q0 = sg[i0];
  } else {
    #pragma unroll
    for (int c = 0; c < C; ++c) xi0[c] = 0.f;
  }
  if (a1){
    #pragma unroll
    for (int c = 0; c < C; ++c) xi1[c] = xg[(size_t)i1*C + c];
    q1 = sg[i1];
  } else {
    #pragma unroll
    for (int c = 0; c < C; ++c) xi1[c] = 0.f;
  }
  __shared__ float xs[TJ*C];
  __shared__ float ss[TJ];
  float d00 = __builtin_inff(), d01 = __builtin_inff(), d02 = __builtin_inff();
  float d10 = __builtin_inff(), d11 = __builtin_inff(), d12 = __builtin_inff();
  int n00 = 0, n01 = 0, n02 = 0;
  int n10 = 0, n11 = 0, n12 = 0;

  int jbase = s*csize;
  int jend  = min(n_per, jbase + csize);
  for (int t0 = jbase; t0 < jend; t0 += TJ){
    int lim = min(TJ, jend - t0);
    __syncthreads();
    for (int idx = tid; idx < lim*C; idx += 64) xs[idx] = xg[(size_t)t0*C + idx];
    for (int idx = tid; idx < lim;   idx += 64) ss[idx] = sg[t0 + idx];
    __syncthreads();
    for (int jj = 0; jj < lim; ++jj){
      const float4* xr = (const float4*)(xs + jj*C);
      float p0a=0,p0b=0,p0c=0,p0d=0;
      float p1a=0,p1b=0,p1c=0,p1d=0;
      #pragma unroll
      for (int c4 = 0; c4 < C/4; ++c4){
        float4 w = xr[c4];
        p0a += xi0[4*c4+0]*w.x; p0b += xi0[4*c4+1]*w.y;
        p0c += xi0[4*c4+2]*w.z; p0d += xi0[4*c4+3]*w.w;
        p1a += xi1[4*c4+0]*w.x; p1b += xi1[4*c4+1]*w.y;
        p1c += xi1[4*c4+2]*w.z; p1d += xi1[4*c4+3]*w.w;
      }
      int j = t0 + jj;
      float dv0 = q0 + ss[jj] - 2.f*((p0a+p0b)+(p0c+p0d));
      float dv1 = q1 + ss[jj] - 2.f*((p1a+p1b)+(p1c+p1d));
      if (a0 && j != i0) top3i(dv0, j, d00,d01,d02, n00,n01,n02);
      if (a1 && j != i1) top3i(dv1, j, d10,d11,d12, n10,n11,n12);
    }
  }
  if (a0){
    size_t o = ((size_t)(g*n_per + i0)*nsplit + s)*3;
    partd[o+0]=d00; partd[o+1]=d01; partd[o+2]=d02;
    parti[o+0]=n00; parti[o+1]=n01; parti[o+2]=n02;
  }
  if (a1){
    size_t o = ((size_t)(g*n_per + i1)*nsplit + s)*3;
    partd[o+0]=d10; partd[o+1]=d11; partd[o+2]=d12;
    parti[o+0]=n10; parti[o+1]=n11; parti[o+2]=n12;
  }
}

// 1-row/thread variant for C=64 (xi=64 floats + overhead fits ~95 VGPR, no spill)

template<int C, int TJ>
__global__ __launch_bounds__(64) void k_knn1r(
    const float* __restrict__ x, const float* __restrict__ sq,
    int n_per, int bpg, int nsplit, int csize,
    float* __restrict__ partd, int* __restrict__ parti)
{
  int bid  = blockIdx.x;
  int s    = bid % nsplit;
  int b2i  = bid / nsplit;
  int g    = b2i / bpg;
  int tile = b2i % bpg;
  int tid  = threadIdx.x;
  int i0 = tile*64 + tid;
  const float* xg = x  + (size_t)g*n_per*C;
  const float* sg = sq + (size_t)g*n_per;
  float xi0[C];
  #pragma unroll
  for (int c = 0; c < C; ++c) xi0[c] = xg[(size_t)i0*C + c];
  float q0 = sg[i0];

  __shared__ float xs[TJ*C];
  __shared__ float ss[TJ];
  float d00 = __builtin_inff(), d01 = __builtin_inff(), d02 = __builtin_inff();
  int n00 = 0, n01 = 0, n02 = 0;

  int jbase = s*csize;
  int jend  = min(n_per, jbase + csize);
  for (int t0 = jbase; t0 < jend; t0 += TJ){
    int lim = min(TJ, jend - t0);
    __syncthreads();
    for (int idx = tid; idx < lim*C; idx += 64) xs[idx] = xg[(size_t)t0*C + idx];
    for (int idx = tid; idx < lim;   idx += 64) ss[idx] = sg[t0 + idx];
    __syncthreads();
    for (int jj = 0; jj < lim; ++jj){
      const float4* xr = (const float4*)(xs + jj*C);
      float p0a=0,p0b=0,p0c=0,p0d=0;
      #pragma unroll
      for (int c4 = 0; c4 < C/4; ++c4){
        float4 w = xr[c4];
        p0a += xi0[4*c4+0]*w.x; p0b += xi0[4*c4+1]*w.y;
        p0c += xi0[4*c4+2]*w.z; p0d += xi0[4*c4+3]*w.w;
      }
      int j = t0 + jj;
      float dv0 = q0 + ss[jj] - 2.f*((p0a+p0b)+(p0c+p0d));
      if (j != i0) top3i(dv0, j, d00,d01,d02, n00,n01,n02);
    }
  }
  size_t o = ((size_t)(g*n_per + i0)*nsplit + s)*3;
  partd[o+0]=d00; partd[o+1]=d01; partd[o+2]=d02;
  parti[o+0]=n00; parti[o+1]=n01; parti[o+2]=n02;
}

__global__ void k_knnmerge(const float* __restrict__ partd, const int* __restrict__ parti,
                           int n_total, int n_per, int nsplit, int* __restrict__ nbr)
{
  int row = blockIdx.x*256 + threadIdx.x;
  if (row >= n_total) return;
  float d0 = __builtin_inff(), d1 = __builtin_inff(), d2 = __builtin_inff();
  int j0 = 0, j1 = 0, j2 = 0;
  for (int s = 0; s < nsplit; ++s){
    for (int q = 0; q < 3; ++q){
      size_t o = ((size_t)row*nsplit + s)*3 + q;
      float d = partd[o]; int j = parti[o];
      top3t(d, j, d0,d1,d2, j0,j1,j2);
    }
  }
  int g = row / n_per;
  nbr[row*3+0] = g*n_per + clampi(j0, 0, n_per-1);
  nbr[row*3+1] = g*n_per + clampi(j1, 0, n_per-1);
  nbr[row*3+2] = g*n_per + clampi(j2, 0, n_per-1);
}

// ---------------- Chebyshev conv pieces (r13 frozen) ----------------

__global__ void k_chebwn(const float* __restrict__ w, const int* __restrict__ nbr,
                         float* __restrict__ wn, int ne, int n){
  int e = blockIdx.x*256 + threadIdx.x;
  if (e >= ne) return;
  int i = e/3;
  int s = clampi(nbr[e], 0, n-1);
  float sd = w[3*i] + w[3*i+1] + w[3*i+2];
  float sv = w[3*s] + w[3*s+1] + w[3*s+2];
  float dnd = (sd > 0.f) ? 1.f / sqrtf(fmaxf(sd, 1e-12f)) : 0.f;
  float dns = (sv > 0.f) ? 1.f / sqrtf(fmaxf(sv, 1e-12f)) : 0.f;
  wn[e] = w[e] * dnd * dns;
}

template<int C>
__global__ void k_lap(const float* __restrict__ v, const float* __restrict__ zp,
                      const float* __restrict__ wn, const int* __restrict__ nbr,
                      float* __restrict__ out, int total, float aa, float bb)
{
  int idx = blockIdx.x*256 + threadIdx.x;
  if (idx >= total) return;
  int i = idx / C;
  int c = idx - i*C;
  int e = i*3;
  int nmax = total / C;
  int s0 = clampi(nbr[e+0], 0, nmax-1);
  int s1 = clampi(nbr[e+1], 0, nmax-1);
  int s2 = clampi(nbr[e+2], 0, nmax-1);
  float s = wn[e+0]*v[(size_t)s0*C + c]
          + wn[e+1]*v[(size_t)s1*C + c]
          + wn[e+2]*v[(size_t)s2*C + c];
  float r = -aa*s;
  if (bb != 0.f) r += bb*zp[idx];
  out[idx] = r;
}

// ---------------- generic tiled matmul (r13 frozen) ----------------

struct In4 { const float* p0; const float* p1; const float* p2; const float* p3; };

template<int ACT, int NIN>
__global__ __launch_bounds__(256) void k_mm(
    In4 ins, const float* __restrict__ W,
    const float* __restrict__ bias, float* __restrict__ out,
    int nrows, int cin, int cout)
{
  __shared__ float inl[64][65];
  __shared__ float wl[64][64];
  int r0 = blockIdx.x * 64;
  int c0 = blockIdx.y * 64;
  int tid = threadIdx.x;
  int tr = tid & 15, tc = tid >> 4;
  float acc[4][4] = {{0,0,0,0},{0,0,0,0},{0,0,0,0},{0,0,0,0}};
  const float* inp[4] = {ins.p0, ins.p1, ins.p2, ins.p3};
  for (int ni = 0; ni < NIN; ++ni){
    const float* A = inp[ni];
    const float* Wb = W + (size_t)ni*cin*cout;
    for (int k0 = 0; k0 < cin; k0 += 64){
      int klim = min(64, cin - k0);
      __syncthreads();
      for (int idx = tid; idx < 64*64; idx += 256){
        int rr = idx >> 6, kk = idx & 63;
        float v = 0.f;
        if (r0 + rr < nrows && kk < klim) v = A[(size_t)(r0+rr)*cin + k0 + kk];
        inl[rr][kk] = v;
      }
      for (int idx = tid; idx < 64*64; idx += 256){
        int kk = idx >> 6, jj = idx & 63;
        float v = 0.f;
        if (kk < klim && c0 + jj < cout) v = Wb[(size_t)(k0+kk)*cout + c0 + jj];
        wl[kk][jj] = v;
      }
      __syncthreads();
      for (int kk = 0; kk < 64; ++kk){
        float4 wv = *(const float4*)&wl[kk][tc*4];
        float a0v = inl[tr*4+0][kk];
        float a1v = inl[tr*4+1][kk];
        float a2v = inl[tr*4+2][kk];
        float a3v = inl[tr*4+3][kk];
        acc[0][0] += a0v*wv.x; acc[0][1] += a0v*wv.y; acc[0][2] += a0v*wv.z; acc[0][3] += a0v*wv.w;
        acc[1][0] += a1v*wv.x; acc[1][1] += a1v*wv.y; acc[1][2] += a1v*wv.z; acc[1][3] += a1v*wv.w;
        acc[2][0] += a2v*wv.x; acc[2][1] += a2v*wv.y; acc[2][2] += a2v*wv.z; acc[2][3] += a2v*wv.w;
        acc[3][0] += a3v*wv.x; acc[3][1] += a3v*wv.y; acc[3][2] += a3v*wv.z; acc[3][3] += a3v*wv.w;
      }
    }
  }
  #pragma unroll
  for (int q = 0; q < 4; ++q){
    int r = r0 + tr*4 + q;
    if (r >= nrows) continue;
    #pragma unroll
    for (int p = 0; p < 4; ++p){
      int j = c0 + tc*4 + p;
      if (j >= cout) continue;
      float v = acc[q][p] + bias[j];
      if (ACT == 1) v = fmaxf(v, 0.f);
      if (ACT == 2) v = 1.0507009873554805f * (v > 0.f ? v : 1.6732632423543772f * expm1f(v));
      out[(size_t)r*cout + j] = v;
    }
  }
}

// ---------------- GraphNorm (r13 frozen, non-atomic) ----------------

__global__ void k_gnstat(const float* __restrict__ x, float* __restrict__ msum_p,
                         float* __restrict__ m2sum_p)
{
  int g = blockIdx.x >> 4, chunk = blockIdx.x & 15;
  int c = threadIdx.x & 63, q = threadIdx.x >> 6;
  const float* xg = x + (size_t)g*4096*64;
  int nb = chunk*256;
  float s1 = 0.f, s2 = 0.f;
  for (int n = nb + q; n < nb + 256; n += 4){
    float v = xg[(size_t)n*64 + c];
    s1 += v; s2 += v*v;
  }
  __shared__ float r1[4][64], r2[4][64];
  r1[q][c] = s1; r2[q][c] = s2;
  __syncthreads();
  if (q == 0){
    msum_p [(g*16 + chunk)*64 + c] = r1[0][c]+r1[1][c]+r1[2][c]+r1[3][c];
    m2sum_p[(g*16 + chunk)*64 + c] = r2[0][c]+r2[1][c]+r2[2][c]+r2[3][c];
  }
}

__global__ void k_gnapply(float* __restrict__ x, const float* __restrict__ msum_p,
                          const float* __restrict__ m2sum_p,
                          const float* __restrict__ alpha, const float* __restrict__ gamma,
                          const float* __restrict__ beta)
{
  int idx = blockIdx.x*256 + threadIdx.x;
  if (idx >= 32768*64) return;
  int c = idx & 63;
  int node = idx >> 6;
  int g = node >> 12;
  float ms = 0.f, m2 = 0.f;
  for (int ch = 0; ch < 16; ++ch){
    ms += msum_p [(g*16 + ch)*64 + c];
    m2 += m2sum_p[(g*16 + ch)*64 + c];
  }
  float m  = ms * (1.f/4096.f);
  float e2 = m2 * (1.f/4096.f);
  float al = alpha[c];
  float var = e2 - (2.f*al - al*al)*m*m;
  float sub = x[idx] - al*m;
  x[idx] = gamma[c] * sub * (1.f/sqrtf(fmaxf(var, 0.f) + 1e-5f)) + beta[c];
}

// ---------------- softmax + DiffPool (r13 frozen) ----------------

__global__ void k_softmax(const float* __restrict__ u, float* __restrict__ S, int n){
  int i = blockIdx.x*256 + threadIdx.x;
  if (i >= n) return;
  const float* r = u + (size_t)i*100;
  float* o = S + (size_t)i*100;
  float lr[100];
  float m = -__builtin_inff();
  for (int j = 0; j < 100; ++j){ lr[j] = r[j]; m = fmaxf(m, lr[j]); }
  float ssum = 0.f;
  for (int j = 0; j < 100; ++j){ lr[j] = expf(lr[j] - m); ssum += lr[j]; }
  float inv = 1.f / ssum;
  for (int j = 0; j < 100; ++j) o[j] = lr[j] * inv;
}

__global__ void k_pool(const float* __restrict__ S, const float* __restrict__ xf,
                       float* __restrict__ PT)
{
  int g = blockIdx.x >> 4, chunk = blockIdx.x & 15;
  int tid = threadIdx.x;
  __shared__ float Sl[64*100];
  __shared__ float Xl[64*32];
  float acc[13];
  int mq[13], cq[13];
  int base = tid*13;
  #pragma unroll
  for (int q = 0; q < 13; ++q){
    acc[q] = 0.f;
    int oi = base + q;
    mq[q] = (oi < 3300) ? oi/33 : 0;
    cq[q] = (oi < 3300) ? oi%33 : 0;
  }
  const float* Sg = S  + ((size_t)g*4096 + chunk*256)*100;
  const float* Xg = xf + ((size_t)g*4096 + chunk*256)*32;
  for (int n0 = 0; n0 < 256; n0 += 64){
    __syncthreads();
    for (int idx = tid; idx < 6400; idx += 256) Sl[idx] = Sg[(size_t)n0*100 + idx];
    for (int idx = tid; idx < 2048; idx += 256) Xl[idx] = Xg[(size_t)n0*32 + idx];
    __syncthreads();
    for (int nn = 0; nn < 64; ++nn){
      #pragma unroll
      for (int q = 0; q < 13; ++q){
        int ci = cq[q] & 31;
        float xv = Xl[nn*32 + ci];
        if (cq[q] == 32) xv = 1.f;
        acc[q] += Sl[nn*100 + mq[q]] * xv;
      }
    }
  }
  #pragma unroll
  for (int q = 0; q < 13; ++q){
    int oi = base + q;
    if (oi < 3300) atomicAdd(&PT[(size_t)g*3300 + oi], acc[q]);
  }
}

__global__ void k_xp(const float* __restrict__ PT, float* __restrict__ xp){
  int i = blockIdx.x*256 + threadIdx.x;
  if (i >= 800*32) return;
  int bm = i >> 5, c = i & 31;
  xp[i] = PT[(size_t)bm*33 + c] / PT[(size_t)bm*33 + 32];
}

// ---------------- PPI EdgeConv ----------------

__global__ void k_ppi(const float* __restrict__ xp, const int* __restrict__ connect,
                      const float* __restrict__ W2, const float* __restrict__ b2v,
                      int* __restrict__ hraw)
{
  int idx = blockIdx.x*256 + threadIdx.x;
  if (idx >= 8*600*64) return;
  int c  = idx & 63;
  int eg = idx >> 6;
  int b  = eg / 600, e = eg - b*600;
  int sI = b*100 + clampi(connect[e],       0, 99);
  int dI = b*100 + clampi(connect[600 + e], 0, 99);
  float acc = b2v[c];
  #pragma unroll
  for (int t = 0; t < 32; ++t) acc += xp[(size_t)dI*32 + t] * W2[t*64 + c];
  #pragma unroll
  for (int t = 0; t < 32; ++t) acc += (xp[(size_t)sI*32 + t] - xp[(size_t)dI*32 + t]) * W2[(32+t)*64 + c];
  float r = fmaxf(acc, 0.f);
  atomicMax(&hraw[(size_t)dI*64 + c], __float_as_int(r));
}

__global__ void k_hfin(const int* __restrict__ hraw, float* __restrict__ h, int n){
  int i = blockIdx.x*256 + threadIdx.x;
  if (i >= n) return;
  float v = __int_as_float(hraw[i]);
  h[i] = (v < -1e37f) ? 0.f : v;
}

// ---------------- Dynamic EdgeConv + residual ----------------

__global__ void k_dyn(const float* __restrict__ h, const int* __restrict__ nbr3,
                      const float* __restrict__ W3, const float* __restrict__ b3v,
                      float* __restrict__ z)
{
  int idx = blockIdx.x*256 + threadIdx.x;
  if (idx >= 800*64) return;
  int c = idx & 63, i = idx >> 6;
  float base = b3v[c];
  for (int t = 0; t < 64; ++t) base += h[(size_t)i*64 + t] * W3[t*64 + c];
  float mx = 0.f;
  for (int k = 0; k < 3; ++k){
    int sI = clampi(nbr3[i*3 + k], 0, 799);
    float acc = base;
    for (int t = 0; t < 64; ++t) acc += (h[(size_t)sI*64 + t] - h[(size_t)i*64 + t]) * W3[(64+t)*64 + c];
    mx = fmaxf(mx, fmaxf(acc, 0.f));
  }
  z[idx] = h[idx] + mx;
}

// ---------------- host launch ----------------

extern "C" void kernel_launch(void* const* d_in, const int* in_sizes, int n_in,
                              void* d_out, int out_size, void* d_ws, size_t ws_size,
                              hipStream_t stream)
{
  const size_t REQ_SMALL = 11785728ull * 4ull;     // 45.0 MiB (chunked path)
  const size_t REQ_BIG   = 31854592ull * 4ull;     // 121.5 MiB (dechunked path)
  if (ws_size < REQ_SMALL || n_in < 27){
    int nb = (out_size + 255)/256;
    k_fillf<<<nb, 256, 0, stream>>>((float*)d_out, out_size, (float)ws_size);
    return;
  }
  const bool big = (ws_size >= REQ_BIG);           // constant per deployment -> capture-safe

  const float* x    = (const float*)d_in[0];
  const float* ew   = (const float*)d_in[1];
  const int*  connect = (const int*)d_in[3];
  const float* W0  = (const float*)d_in[4];
  const float* b0  = (const float*)d_in[5];
  const float* gal = (const float*)d_in[6];
  const float* gga = (const float*)d_in[7];
  const float* gbe = (const float*)d_in[8];
  const float* W1  = (const float*)d_in[9];
  const float* b1c = (const float*)d_in[10];
  const float* f1w1=(const float*)d_in[11]; const float* f1b1=(const float*)d_in[12];
  const float* f1w2=(const float*)d_in[13]; const float* f1b2=(const float*)d_in[14];
  const float* f1w3=(const float*)d_in[15]; const float* f1b3=(const float*)d_in[16];
  const float* W2  = (const float*)d_in[17]; const float* b2v=(const float*)d_in[18];
  const float* W3  = (const float*)d_in[19]; const float* b3v=(const float*)d_in[20];
  const float* f2w1=(const float*)d_in[21]; const float* f2b1=(const float*)d_in[22];
  const float* f2w2=(const float*)d_in[23]; const float* f2b2=(const float*)d_in[24];
  const float* f2w3=(const float*)d_in[25]; const float* f2b3=(const float*)d_in[26];

  float* ws   = (float*)d_ws;
  float* u0   = ws;                       // 2,097,152   (N x 64)
  float* Za   = ws +  2097152;            // 2,097,152
  float* Zb   = ws +  4194304;            // 2,097,152
  float* Zc   = ws +  6291456;            // 2,097,152 (ends 8,388,608)
  float* acc  = ws +  8388608;            // chunked: 4096x400 | big: 32768x400
  float* h1   = big ? (ws + 21495808) : (acc + 1638400);
  float* h2   = big ? (ws + 28049408) : (acc + 2457600);
  float* partd= Za;                       // knn partials in dead Za/Zb (nsplit=8: 786,432)
  int*   parti= (int*)Zb;
  float* Sb   = Za;                       // 3,276,800 (aliases Za+Zb, post-conv)
  float* sm   = big ? (ws + 31326208) : (ws + 11272192);  // smalls (528,384)
  float* sqb  = sm;                       // 32,768 (also GN partials: 16,384 used)
  int*   nbr  = (int*)(sm + 163840);      // 98,304
  int*   nbr3 = (int*)(sm + 262144);      // 2,400
  float* PT   = sm + 266240;              // 26,400
  float* xp   = sm + 294912;              // 25,600
  int*   hraw = (int*)(sm + 320512);      // 51,200
  float* hb   = sm + 371712;              // 51,200
  float* zb   = sm + 422912;              // 51,200
  float* g1   = sm + 474112;              // 25,600
  float* g2   = sm + 499712;              // 12,800
  float* wnb  = sm + 65536;               // 98,304

  float* ub   = (float*)d_out;            // u: 3,276,800 fp32
  float* vout = ub + 3276800;             // v: 12,800 fp32

  const int N = 32768;

  // 1) kNN #1 on x (C=32): 64-thr registerized, TJ=64 (8.4KB LDS -> high occ)
  k_sqnorm<<<128, 256, 0, stream>>>(x, sqb, N, 32);
  k_knn<32,64><<<2048, 64, 0, stream>>>(x, sqb, 4096, 32, 8, 512, partd, parti);
  k_knnmerge<<<128, 256, 0, stream>>>(partd, parti, N, 4096, 8, nbr);

  // 2) cheb normalization (dn fused into chebwn)
  k_chebwn<<<384, 256, 0, stream>>>(ew, nbr, wnb, 3*N, N);

  // 3) conv0: Z recurrence (C=32), fused matmul 4x(32->64)
  k_lap<32><<<4096, 256, 0, stream>>>(x, x, wnb, nbr, Za, N*32, 1.f, 0.f);
  k_lap<32><<<4096, 256, 0, stream>>>(Za, x, wnb, nbr, Zb, N*32, 2.f, -1.f);
  k_lap<32><<<4096, 256, 0, stream>>>(Zb, Za, wnb, nbr, Zc, N*32, 2.f, -1.f);
  {
    In4 ins{x, Za, Zb, Zc};
    k_mm<0,4><<<dim3(512,1), 256, 0, stream>>>(ins, W0, b0, u0, N, 32, 64);
  }

  // 4) GraphNorm (non-atomic partials in sqb)
  k_gnstat<<<128, 256, 0, stream>>>(u0, sqb, sqb + 8192);
  k_gnapply<<<8192, 256, 0, stream>>>(u0, sqb, sqb + 8192, gal, gga, gbe);

  // 5) kNN #2 on u0 (C=64): 64-thr registerized, 1 row/thread, TJ=32
  k_sqnorm<<<128, 256, 0, stream>>>(u0, sqb, N, 64);
  k_knn1r<64,32><<<4096, 64, 0, stream>>>(u0, sqb, 4096, 64, 8, 512, partd, parti);
  k_knnmerge<<<128, 256, 0, stream>>>(partd, parti, N, 4096, 8, nbr);
  k_chebwn<<<384, 256, 0, stream>>>(ew, nbr, wnb, 3*N, N);

  // 6) conv1 Z recurrence (C=64)
  k_lap<64><<<8192, 256, 0, stream>>>(u0, u0, wnb, nbr, Za, N*64, 1.f, 0.f);
  k_lap<64><<<8192, 256, 0, stream>>>(Za, u0, wnb, nbr, Zb, N*64, 2.f, -1.f);
  k_lap<64><<<8192, 256, 0, stream>>>(Zb, Za, wnb, nbr, Zc, N*64, 2.f, -1.f);

  // 7) conv1-matmul + fc1 -> u in d_out. Dechunked when ws allows.
  {
    int nch  = big ? 1 : 8;
    int rows = big ? N : 4096;
    int gx   = big ? 512 : 64;
    for (int ch = 0; ch < nch; ++ch){
      size_t o64  = (size_t)ch*4096*64;
      size_t o100 = (size_t)ch*4096*100;
      In4 ic{u0 + o64, Za + o64, Zb + o64, Zc + o64};
      k_mm<0,4><<<dim3(gx,7), 256, 0, stream>>>(ic, W1, b1c, acc, rows, 64, 400);
      In4 i1{acc, nullptr, nullptr, nullptr};
      k_mm<2,1><<<dim3(gx,4), 256, 0, stream>>>(i1, f1w1, f1b1, h1, rows, 400, 200);
      In4 i2{h1, nullptr, nullptr, nullptr};
      k_mm<2,1><<<dim3(gx,2), 256, 0, stream>>>(i2, f1w2, f1b2, h2, rows, 200, 100);
      In4 i3{h2, nullptr, nullptr, nullptr};
      k_mm<0,1><<<dim3(gx,2), 256, 0, stream>>>(i3, f1w3, f1b3, ub + o100, rows, 100, 100);
    }
  }

  // 8) DiffPool
  k_softmax<<<128, 256, 0, stream>>>(ub, Sb, N);
  k_zero<<<104, 256, 0, stream>>>(PT, 26400);
  k_pool<<<128, 256, 0, stream>>>(Sb, x, PT);
  k_xp<<<100, 256, 0, stream>>>(PT, xp);

  // 9) PPI EdgeConv
  k_filli<<<200, 256, 0, stream>>>(hraw, 51200, (int)0xFF800000);
  k_ppi<<<1200, 256, 0, stream>>>(xp, connect, W2, b2v, hraw);
  k_hfin<<<200, 256, 0, stream>>>(hraw, hb, 51200);

  // 10) Dynamic EdgeConv (small, legacy path)
  k_sqnorm<<<4, 256, 0, stream>>>(hb, sqb, 800, 64);
  k_knn<64,64><<<8, 64, 0, stream>>>(hb, sqb, 100, 1, 1, 100, partd, parti);
  k_knnmerge<<<4, 256, 0, stream>>>(partd, parti, 800, 100, 1, nbr3);
  k_dyn<<<200, 256, 0, stream>>>(hb, nbr3, W3, b3v, zb);

  // 11) fc2 -> v in d_out
  {
    In4 j1{zb, nullptr, nullptr, nullptr};
    k_mm<2,1><<<dim3(13,1), 256, 0, stream>>>(j1, f2w1, f2b1, g1, 800, 64, 32);
    In4 j2{g1, nullptr, nullptr, nullptr};
    k_mm<2,1><<<dim3(13,1), 256, 0, stream>>>(j2, f2w2, f2b2, g2, 800, 32, 16);
    In4 j3{g2, nullptr, nullptr, nullptr};
    k_mm<0,1><<<dim3(13,1), 256, 0, stream>>>(j3, f2w3, f2b3, vout, 800, 16, 16);
  }
}